// Round 15
// baseline (75.442 us; speedup 1.0000x reference)
//
#include <hip/hip_runtime.h>
#include <hip/hip_bf16.h>
#include <cstdint>

// Problem constants: B=1024, S=8, H=16, DK=DV=32, D=512
#define NB 1024
#define ND 512
#define NM 8192  // B*S rows

typedef __attribute__((ext_vector_type(8))) short short8;
typedef __attribute__((ext_vector_type(8))) __bf16 bf16x8;
typedef __attribute__((ext_vector_type(4))) float f32x4;
typedef __attribute__((ext_vector_type(4))) unsigned short ushort4v;

__device__ __forceinline__ unsigned short f2bf(float f) {
  uint32_t x = __builtin_bit_cast(uint32_t, f);
  x += 0x7fffu + ((x >> 16) & 1u);  // RNE
  return (unsigned short)(x >> 16);
}
__device__ __forceinline__ float bf2f(unsigned short u) {
  return __builtin_bit_cast(float, (uint32_t)u << 16);
}
__device__ __forceinline__ f32x4 mfma16(short8 a, short8 b, f32x4 c) {
  return __builtin_amdgcn_mfma_f32_16x16x32_bf16(
      __builtin_bit_cast(bf16x8, a), __builtin_bit_cast(bf16x8, b), c, 0, 0, 0);
}
__device__ __forceinline__ short8 cvt8(float4 a, float4 b) {
  short8 r;
  r[0] = (short)f2bf(a.x); r[1] = (short)f2bf(a.y);
  r[2] = (short)f2bf(a.z); r[3] = (short)f2bf(a.w);
  r[4] = (short)f2bf(b.x); r[5] = (short)f2bf(b.y);
  r[6] = (short)f2bf(b.z); r[7] = (short)f2bf(b.w);
  return r;
}
__device__ __forceinline__ void gl_lds16(const unsigned short* g, unsigned short* lds) {
  __builtin_amdgcn_global_load_lds(
      (const __attribute__((address_space(1))) unsigned int*)g,
      (__attribute__((address_space(3))) unsigned int*)lds, 16, 0, 0);
}
#define VMCNT(n) asm volatile("s_waitcnt vmcnt(" #n ")" ::: "memory")
#define LGKM0() asm volatile("s_waitcnt lgkmcnt(0)" ::: "memory")
#define BAR() __builtin_amdgcn_s_barrier()

// ---- fp32 -> bf16 pre-convert: weights only (4 x 262144)
__global__ __launch_bounds__(256) void convert_w(
    const float* __restrict__ Wq, const float* __restrict__ Wk,
    const float* __restrict__ Wv, const float* __restrict__ Wo,
    unsigned short* __restrict__ Wqb, unsigned short* __restrict__ Wkb,
    unsigned short* __restrict__ Wvb, unsigned short* __restrict__ Wob) {
  const int idx = blockIdx.x * 256 + threadIdx.x;
  const int sel = idx >> 15, o = (idx & 32767) * 8;
  const float* src = sel == 0 ? Wq : sel == 1 ? Wk : sel == 2 ? Wv : Wo;
  unsigned short* dst = sel == 0 ? Wqb : sel == 1 ? Wkb : sel == 2 ? Wvb : Wob;
  const float4 a = ((const float4*)(src + o))[0];
  const float4 b = ((const float4*)(src + o))[1];
  *(short8*)(dst + o) = cvt8(a, b);
}

// ==== QKV GEMM: DEMAND-CORNER tile BM=128 x BN=512 (full seg width), BK=32.
// A is read from HBM exactly ONCE (demand: A 50.4 + W 96 + C 25 = 171 MB vs
// 222 of the BN=256 tile). Triple-buffered 3-deep counted-vmcnt pipeline.
// Per wave per tile: A = 2 f32 loads (reg->cvt->ds_write), W = 4 gl_lds.
// Steady queue entering iter t: [A(t+1)x2, W(t+1)x4, A(t+2)x2, W(t+2)x4]=12.
// iter t: compute; VMCNT(10)->A(t+1); WRA; ISSA(t+3); VMCNT(8)->W(t+1);
//         LGKM0; BAR; GLW(t+3).  Tails exact: t=13 VMCNT(6); t=14 VMCNT(4)/(0).
// LDS 120KB (A 3x8KB + W 3x32KB) -> 1 block/CU. Grid 192 = 3 segs x 64 mt.
// 512 threads = 8 waves (2m x 4n), wave tile 64x128, acc 4x8 (32 MFMA/tile).
__global__ __launch_bounds__(512, 2) void gemm_qkv(
    const float* __restrict__ Qf, const float* __restrict__ Kf,
    const float* __restrict__ Vf,
    const unsigned short* __restrict__ Wqb, const unsigned short* __restrict__ Wkb,
    const unsigned short* __restrict__ Wvb,
    const float* __restrict__ bq, const float* __restrict__ bk,
    const float* __restrict__ bv,
    unsigned short* __restrict__ qo, unsigned short* __restrict__ ko,
    unsigned short* __restrict__ vo) {
  __shared__ unsigned short Asb[3][128 * 32];  // 8KB each
  __shared__ unsigned short Wsb[3][512 * 32];  // 32KB each

  const int bid = blockIdx.x;
  const int seg = bid / 64, mt = bid % 64;  // 192 = 3 x 64
  const float* A = seg == 0 ? Qf : seg == 1 ? Kf : Vf;
  const unsigned short* W = seg == 0 ? Wqb : seg == 1 ? Wkb : Wvb;
  const float* bias = seg == 0 ? bq : seg == 1 ? bk : bv;
  unsigned short* C = seg == 0 ? qo : seg == 1 ? ko : vo;
  const int mBase = mt * 128;

  const int tid = threadIdx.x, lane = tid & 63, wid = tid >> 6;
  const int wm = wid >> 2, wn = wid & 3;
  const int l15 = lane & 15, l4 = lane >> 4;

  // A staging: thread -> row ar = tid>>2, k-granule ag = tid&3 (8 f32)
  const int ar = tid >> 2, ag = tid & 3;
  const float* Aptr = A + (size_t)(mBase + ar) * ND + ag * 8;
  // W staging: wave wid stages rows [wid*64, +64) via 4 gl_lds issues;
  // issue i: rows wid*64+i*16 .. +16; lane l -> row +(l>>2), col (l&3)*8.
  const unsigned short* Wsrc =
      W + (size_t)(wid * 64 + (lane >> 2)) * ND + (lane & 3) * 8;

  f32x4 acc[4][8] = {};
  float4 pa[3][2];  // A prefetch reg sets; indices compile-time (unrolled)

#define ISSA(kt)                                                  \
  {                                                               \
    pa[(kt) % 3][0] = *(const float4*)(Aptr + (kt) * 32);         \
    pa[(kt) % 3][1] = *(const float4*)(Aptr + (kt) * 32 + 4);     \
  }
#define WRA(kt)                                                   \
  {                                                               \
    *(short8*)&Asb[(kt) % 3][ar * 32 + ag * 8] =                  \
        cvt8(pa[(kt) % 3][0], pa[(kt) % 3][1]);                   \
  }
#define GLW(kt)                                                            \
  {                                                                        \
    gl_lds16(Wsrc + (size_t)0 * ND + (kt) * 32,                            \
             &Wsb[(kt) % 3][(wid * 64) * 32]);                             \
    gl_lds16(Wsrc + (size_t)16 * ND + (kt) * 32,                           \
             &Wsb[(kt) % 3][(wid * 64 + 16) * 32]);                        \
    gl_lds16(Wsrc + (size_t)32 * ND + (kt) * 32,                           \
             &Wsb[(kt) % 3][(wid * 64 + 32) * 32]);                        \
    gl_lds16(Wsrc + (size_t)48 * ND + (kt) * 32,                           \
             &Wsb[(kt) % 3][(wid * 64 + 48) * 32]);                        \
  }

  auto compute = [&](const unsigned short* AL, const unsigned short* WL) {
    short8 af[4], bf8[8];
#pragma unroll
    for (int mf = 0; mf < 4; ++mf)
      af[mf] = *(const short8*)&AL[(wm * 64 + mf * 16 + l15) * 32 + l4 * 8];
#pragma unroll
    for (int nf = 0; nf < 8; ++nf)
      bf8[nf] = *(const short8*)&WL[(wn * 128 + nf * 16 + l15) * 32 + l4 * 8];
#pragma unroll
    for (int mf = 0; mf < 4; ++mf)
#pragma unroll
      for (int nf = 0; nf < 8; ++nf)
        acc[mf][nf] = mfma16(af[mf], bf8[nf], acc[mf][nf]);
  };

  // prologue: tiles 0,1,2 -> queue [A0:2,W0:4,A1:2,W1:4,A2:2,W2:4] = 18
  ISSA(0); GLW(0);
  ISSA(1); GLW(1);
  ISSA(2); GLW(2);
  VMCNT(16);  // A0 landed
  WRA(0);
  VMCNT(12);  // W0 landed
  LGKM0(); BAR();  // tile 0 ready; queue = 12

#pragma unroll
  for (int t = 0; t < 16; ++t) {
    compute(Asb[t % 3], Wsb[t % 3]);
    if (t < 15) {
      if (t <= 13) { VMCNT(10); } else { VMCNT(4); }  // A(t+1) landed
      WRA(t + 1);
      if (t <= 12) {
        ISSA(t + 3);
        VMCNT(8);   // W(t+1) landed; [A(t+2),W(t+2),A(t+3)] remain
      } else if (t == 13) {
        VMCNT(6);   // W(14) landed; [A15,W15] remain
      } else {
        VMCNT(0);   // t==14: W(15) landed
      }
      LGKM0(); BAR();  // tile t+1 ready; all waves done with tile t
      if (t <= 12) GLW(t + 3);  // overwrite Wsb[t%3] (safe post-barrier)
    }
  }

  // C/D layout: col = lane&15, row = (lane>>4)*4 + r  [verified rounds 1-14]
#pragma unroll
  for (int nf = 0; nf < 8; ++nf) {
    const int gn = wn * 128 + nf * 16 + l15;
    const float bb = bias[gn];
#pragma unroll
    for (int mf = 0; mf < 4; ++mf)
#pragma unroll
      for (int r = 0; r < 4; ++r) {
        const int gm = mBase + wm * 64 + mf * 16 + l4 * 4 + r;
        C[(size_t)gm * ND + gn] = f2bf(acc[mf][nf][r] + bb);
      }
  }
#undef ISSA
#undef WRA
#undef GLW
}

// ==== Wo GEMM + bias + residual(Q): BM=128 x BN=128, BK=32, triple-buffered
// 3-deep gl_lds pipeline (2 ops/tile/wave). LDS 48KB. Grid 256 = 8 x 32.
__global__ __launch_bounds__(512, 3) void gemm_wo(
    const unsigned short* __restrict__ ctx, const unsigned short* __restrict__ Wob,
    const float* __restrict__ bo, const float* __restrict__ Qres,
    float* __restrict__ out) {
  __shared__ unsigned short Asb[3][128 * 32];
  __shared__ unsigned short Wsb[3][128 * 32];

  const int bid = blockIdx.x;
  const int lid = (bid & 7) * 32 + (bid >> 3);  // bijective: 256 = 8*32
  const int mt = lid >> 2, nloc = lid & 3;
  const int mBase = mt * 128, nBase = nloc * 128;

  const int tid = threadIdx.x, lane = tid & 63, wid = tid >> 6;
  const int wm = wid >> 2, wn = wid & 3;
  const int l15 = lane & 15, l4 = lane >> 4;

  const unsigned short* Asrc =
      ctx + (size_t)(mBase + wid * 16 + (lane >> 2)) * ND + (lane & 3) * 8;
  const unsigned short* Wsrc =
      Wob + (size_t)(nBase + wid * 16 + (lane >> 2)) * ND + (lane & 3) * 8;

  f32x4 acc[4][2] = {};

#define GLAW(kt)                                              \
  {                                                           \
    gl_lds16(Asrc + (kt) * 32, &Asb[(kt) % 3][wid * 512]);    \
    gl_lds16(Wsrc + (kt) * 32, &Wsb[(kt) % 3][wid * 512]);    \
  }

  auto compute = [&](const unsigned short* AL, const unsigned short* WL) {
    short8 af[4], bf4[2];
#pragma unroll
    for (int mf = 0; mf < 4; ++mf)
      af[mf] = *(const short8*)&AL[(wm * 64 + mf * 16 + l15) * 32 + l4 * 8];
#pragma unroll
    for (int nf = 0; nf < 2; ++nf)
      bf4[nf] = *(const short8*)&WL[(wn * 32 + nf * 16 + l15) * 32 + l4 * 8];
#pragma unroll
    for (int mf = 0; mf < 4; ++mf)
#pragma unroll
      for (int nf = 0; nf < 2; ++nf)
        acc[mf][nf] = mfma16(af[mf], bf4[nf], acc[mf][nf]);
  };

  GLAW(0); GLAW(1); GLAW(2);
  VMCNT(4);  // tile 0 landed
  BAR();

#pragma unroll
  for (int t = 0; t < 16; ++t) {
    compute(Asb[t % 3], Wsb[t % 3]);
    if (t < 15) {
      if (t <= 13) { VMCNT(2); } else { VMCNT(0); }
      BAR();
      if (t <= 12) GLAW(t + 3);
    }
  }

#pragma unroll
  for (int nf = 0; nf < 2; ++nf) {
    const int gn = nBase + wn * 32 + nf * 16 + l15;
    const float bb = bo[gn];
#pragma unroll
    for (int mf = 0; mf < 4; ++mf)
#pragma unroll
      for (int r = 0; r < 4; ++r) {
        const int gm = mBase + wm * 64 + mf * 16 + l4 * 4 + r;
        out[(size_t)gm * ND + gn] =
            acc[mf][nf][r] + bb + Qres[(size_t)gm * ND + gn];
      }
  }
#undef GLAW
}

// ---- attention: one wave per (b,h); lane -> (i=lane>>3, j=lane&7)
__global__ __launch_bounds__(256) void attn_kernel(
    const unsigned short* __restrict__ q, const unsigned short* __restrict__ k,
    const unsigned short* __restrict__ v, const int* __restrict__ mask,
    const float* __restrict__ hyper, float* __restrict__ wout,
    unsigned short* __restrict__ ctx) {
  const int tid = threadIdx.x;
  const int wid = tid >> 6, lane = tid & 63;
  const int t = blockIdx.x * 4 + wid;  // b*16 + h
  const int b = t >> 4, h = t & 15;
  const int i = lane >> 3, j = lane & 7;

  const unsigned short* qrow = q + (size_t)(b * 8 + i) * ND + h * 32;
  const unsigned short* krow = k + (size_t)(b * 8 + j) * ND + h * 32;
  float dot = 0.f;
#pragma unroll
  for (int c = 0; c < 4; ++c) {
    const short8 qv = ((const short8*)qrow)[c];
    const short8 kv = ((const short8*)krow)[c];
#pragma unroll
    for (int e = 0; e < 8; ++e)
      dot += bf2f((unsigned short)qv[e]) * bf2f((unsigned short)kv[e]);
  }
  float score = dot * 0.17677669529663687f;  // 1/sqrt(32)
  if (mask[b * 64 + i * 8 + j]) score = -1e9f;

  float mx = score;
#pragma unroll
  for (int o = 4; o; o >>= 1) mx = fmaxf(mx, __shfl_xor(mx, o, 8));
  const float e = __expf(score - mx);
  float sm = e;
#pragma unroll
  for (int o = 4; o; o >>= 1) sm += __shfl_xor(sm, o, 8);
  const float w = e / sm;
  wout[(size_t)t * 64 + lane] = w;

  const int d0 = (lane & 7) * 4;
  float c0 = 0, c1 = 0, c2 = 0, c3 = 0;
#pragma unroll
  for (int jj = 0; jj < 8; ++jj) {
    const float wj = __shfl(w, jj, 8);
    const ushort4v vv = *(const ushort4v*)(v + (size_t)(b * 8 + jj) * ND + h * 32 + d0);
    c0 += wj * bf2f(vv[0]); c1 += wj * bf2f(vv[1]);
    c2 += wj * bf2f(vv[2]); c3 += wj * bf2f(vv[3]);
  }
  const float4 hv = *(const float4*)(hyper + (size_t)b * 4096 + h * 256 + i * 32 + d0);
  ushort4v co;
  co[0] = f2bf(c0 * hv.x); co[1] = f2bf(c1 * hv.y);
  co[2] = f2bf(c2 * hv.z); co[3] = f2bf(c3 * hv.w);
  *(ushort4v*)(ctx + (size_t)(b * 8 + i) * ND + h * 32 + d0) = co;
}

// ---- in-place: io = LN(io) * g + b  (residual+bias already fused into gemm_wo)
__global__ __launch_bounds__(256) void ln_kernel(float* __restrict__ io,
                                                 const float* __restrict__ g,
                                                 const float* __restrict__ be) {
  const int tid = threadIdx.x, wid = tid >> 6, lane = tid & 63;
  const size_t row = (size_t)blockIdx.x * 4 + wid;
  float* prow = io + row * ND + lane * 8;
  float4 x0 = ((float4*)prow)[0], x1 = ((float4*)prow)[1];
  float s = x0.x + x0.y + x0.z + x0.w + x1.x + x1.y + x1.z + x1.w;
  float sq = x0.x * x0.x + x0.y * x0.y + x0.z * x0.z + x0.w * x0.w +
             x1.x * x1.x + x1.y * x1.y + x1.z * x1.z + x1.w * x1.w;
#pragma unroll
  for (int o = 32; o; o >>= 1) {
    s += __shfl_xor(s, o, 64);
    sq += __shfl_xor(sq, o, 64);
  }
  const float mu = s * (1.f / 512.f);
  const float inv = rsqrtf(sq * (1.f / 512.f) - mu * mu + 1e-5f);
  const float4 g0 = ((const float4*)(g + lane * 8))[0];
  const float4 g1 = ((const float4*)(g + lane * 8))[1];
  const float4 e0 = ((const float4*)(be + lane * 8))[0];
  const float4 e1 = ((const float4*)(be + lane * 8))[1];
  float4 o0, o1;
  o0.x = (x0.x - mu) * inv * g0.x + e0.x; o0.y = (x0.y - mu) * inv * g0.y + e0.y;
  o0.z = (x0.z - mu) * inv * g0.z + e0.z; o0.w = (x0.w - mu) * inv * g0.w + e0.w;
  o1.x = (x1.x - mu) * inv * g1.x + e1.x; o1.y = (x1.y - mu) * inv * g1.y + e1.y;
  o1.z = (x1.z - mu) * inv * g1.z + e1.z; o1.w = (x1.w - mu) * inv * g1.w + e1.w;
  ((float4*)prow)[0] = o0;
  ((float4*)prow)[1] = o1;
}

extern "C" void kernel_launch(void* const* d_in, const int* in_sizes, int n_in,
                              void* d_out, int out_size, void* d_ws, size_t ws_size,
                              hipStream_t stream) {
  const float* Q = (const float*)d_in[0];
  const float* K = (const float*)d_in[1];
  const float* V = (const float*)d_in[2];
  const int* msk = (const int*)d_in[3];
  const float* hyper = (const float*)d_in[4];
  const float* Wq = (const float*)d_in[5];
  const float* bq = (const float*)d_in[6];
  const float* Wk = (const float*)d_in[7];
  const float* bk = (const float*)d_in[8];
  const float* Wv = (const float*)d_in[9];
  const float* bv = (const float*)d_in[10];
  const float* Wo = (const float*)d_in[11];
  const float* bo = (const float*)d_in[12];
  const float* lg = (const float*)d_in[13];
  const float* lb = (const float*)d_in[14];

  float* out = (float*)d_out;           // [8192,512] fp32
  float* wout = out + (size_t)NM * ND;  // [1024,16,8,8] fp32

  const size_t MAT = (size_t)NM * ND;  // elements
  unsigned short* qb = (unsigned short*)d_ws;
  unsigned short* kb = qb + MAT;
  unsigned short* vb = kb + MAT;
  unsigned short* ctxb = vb + MAT;
  unsigned short* Wqb = ctxb + MAT;
  unsigned short* Wkb = Wqb + (size_t)ND * ND;
  unsigned short* Wvb = Wkb + (size_t)ND * ND;
  unsigned short* Wob = Wvb + (size_t)ND * ND;

  convert_w<<<512, 256, 0, stream>>>(Wq, Wk, Wv, Wo, Wqb, Wkb, Wvb, Wob);
  gemm_qkv<<<192, 512, 0, stream>>>(Q, K, V, Wqb, Wkb, Wvb,
                                    bq, bk, bv, qb, kb, vb);
  attn_kernel<<<4096, 256, 0, stream>>>(qb, kb, vb, msk, hyper, wout, ctxb);
  gemm_wo<<<256, 512, 0, stream>>>(ctxb, Wob, bo, Q, out);
  ln_kernel<<<2048, 256, 0, stream>>>(out, lg, lb);
}

// Round 16
// 68.892 us; speedup vs baseline: 1.0951x; 1.0951x over previous
//
#include <hip/hip_runtime.h>
#include <hip/hip_bf16.h>
#include <cstdint>

// Problem constants: B=1024, S=8, H=16, DK=DV=32, D=512
#define NB 1024
#define ND 512
#define NM 8192  // B*S rows

typedef __attribute__((ext_vector_type(8))) short short8;
typedef __attribute__((ext_vector_type(8))) __bf16 bf16x8;
typedef __attribute__((ext_vector_type(4))) float f32x4;
typedef __attribute__((ext_vector_type(4))) unsigned short ushort4v;

__device__ __forceinline__ unsigned short f2bf(float f) {
  uint32_t x = __builtin_bit_cast(uint32_t, f);
  x += 0x7fffu + ((x >> 16) & 1u);  // RNE
  return (unsigned short)(x >> 16);
}
__device__ __forceinline__ float bf2f(unsigned short u) {
  return __builtin_bit_cast(float, (uint32_t)u << 16);
}
__device__ __forceinline__ f32x4 mfma16(short8 a, short8 b, f32x4 c) {
  return __builtin_amdgcn_mfma_f32_16x16x32_bf16(
      __builtin_bit_cast(bf16x8, a), __builtin_bit_cast(bf16x8, b), c, 0, 0, 0);
}
__device__ __forceinline__ short8 cvt8(float4 a, float4 b) {
  short8 r;
  r[0] = (short)f2bf(a.x); r[1] = (short)f2bf(a.y);
  r[2] = (short)f2bf(a.z); r[3] = (short)f2bf(a.w);
  r[4] = (short)f2bf(b.x); r[5] = (short)f2bf(b.y);
  r[6] = (short)f2bf(b.z); r[7] = (short)f2bf(b.w);
  return r;
}
__device__ __forceinline__ void gl_lds16(const unsigned short* g, unsigned short* lds) {
  __builtin_amdgcn_global_load_lds(
      (const __attribute__((address_space(1))) unsigned int*)g,
      (__attribute__((address_space(3))) unsigned int*)lds, 16, 0, 0);
}
#define VMCNT(n) asm volatile("s_waitcnt vmcnt(" #n ")" ::: "memory")
#define LGKM0() asm volatile("s_waitcnt lgkmcnt(0)" ::: "memory")
#define BAR() __builtin_amdgcn_s_barrier()

// ---- fp32 -> bf16 pre-convert: weights only (4 x 262144)
__global__ __launch_bounds__(256) void convert_w(
    const float* __restrict__ Wq, const float* __restrict__ Wk,
    const float* __restrict__ Wv, const float* __restrict__ Wo,
    unsigned short* __restrict__ Wqb, unsigned short* __restrict__ Wkb,
    unsigned short* __restrict__ Wvb, unsigned short* __restrict__ Wob) {
  const int idx = blockIdx.x * 256 + threadIdx.x;
  const int sel = idx >> 15, o = (idx & 32767) * 8;
  const float* src = sel == 0 ? Wq : sel == 1 ? Wk : sel == 2 ? Wv : Wo;
  unsigned short* dst = sel == 0 ? Wqb : sel == 1 ? Wkb : sel == 2 ? Wvb : Wob;
  const float4 a = ((const float4*)(src + o))[0];
  const float4 b = ((const float4*)(src + o))[1];
  *(short8*)(dst + o) = cvt8(a, b);
}

// ==== QKV GEMM: BM=128 x BN=256, BK=32, 16 K-tiles — TRIPLE-buffered, 3-deep
// counted-vmcnt pipeline. Demand-optimal under {grid>=256, 2 blocks/CU}:
// A f32 100.8 + W 96 + C 25 = 222 MB. (BN=512 corner measured WORSE, R15:
// grid 192 @ 1 block/CU loses more to coverage than 51 MB of demand buys.)
// Per wave per tile: A = 2 f32 loads (reg->cvt->ds_write), W = 2 gl_lds.
// Steady queue entering iter t: [A(t+1)x2, W(t+1)x2, A(t+2)x2, W(t+2)x2] = 8.
// LDS 72KB (3 x 24KB) -> 2 blocks/CU. Grid 384 = 8 XCDs x 48 chunked.
__global__ __launch_bounds__(512, 2) void gemm_qkv(
    const float* __restrict__ Qf, const float* __restrict__ Kf,
    const float* __restrict__ Vf,
    const unsigned short* __restrict__ Wqb, const unsigned short* __restrict__ Wkb,
    const unsigned short* __restrict__ Wvb,
    const float* __restrict__ bq, const float* __restrict__ bk,
    const float* __restrict__ bv,
    unsigned short* __restrict__ qo, unsigned short* __restrict__ ko,
    unsigned short* __restrict__ vo) {
  __shared__ unsigned short Asb[3][128 * 32];  // 8KB each
  __shared__ unsigned short Wsb[3][256 * 32];  // 16KB each

  const int bid = blockIdx.x;
  const int lid = (bid & 7) * 48 + (bid >> 3);  // bijective: 384 = 8*48
  const int mt = lid / 6, np = lid % 6;
  const int seg = np >> 1, nloc = np & 1;
  const float* A = seg == 0 ? Qf : seg == 1 ? Kf : Vf;
  const unsigned short* W = seg == 0 ? Wqb : seg == 1 ? Wkb : Wvb;
  const float* bias = seg == 0 ? bq : seg == 1 ? bk : bv;
  unsigned short* C = seg == 0 ? qo : seg == 1 ? ko : vo;
  const int mBase = mt * 128, nBase = nloc * 256;

  const int tid = threadIdx.x, lane = tid & 63, wid = tid >> 6;
  const int wm = wid >> 2, wn = wid & 3;
  const int l15 = lane & 15, l4 = lane >> 4;

  // A staging: thread -> row ar = tid>>2, k-granule ag = tid&3 (8 f32)
  const int ar = tid >> 2, ag = tid & 3;
  const float* Aptr = A + (size_t)(mBase + ar) * ND + ag * 8;
  // W staging: wave wid stages rows [wid*32, +32) via 2 gl_lds issues;
  // lane l -> row +l>>2, col granule (l&3)*8 — linear row-major [256][32].
  const unsigned short* Wsrc0 =
      W + (size_t)(nBase + wid * 32 + (lane >> 2)) * ND + (lane & 3) * 8;
  const unsigned short* Wsrc1 = Wsrc0 + (size_t)16 * ND;

  f32x4 acc[4][4] = {};
  float4 pa[3][2];  // A prefetch reg sets; indices always compile-time (unrolled)

#define ISSA(kt)                                                  \
  {                                                               \
    pa[(kt) % 3][0] = *(const float4*)(Aptr + (kt) * 32);         \
    pa[(kt) % 3][1] = *(const float4*)(Aptr + (kt) * 32 + 4);     \
  }
#define WRA(kt)                                                   \
  {                                                               \
    *(short8*)&Asb[(kt) % 3][ar * 32 + ag * 8] =                  \
        cvt8(pa[(kt) % 3][0], pa[(kt) % 3][1]);                   \
  }
#define GLW(kt)                                                   \
  {                                                               \
    gl_lds16(Wsrc0 + (kt) * 32, &Wsb[(kt) % 3][wid * 1024]);      \
    gl_lds16(Wsrc1 + (kt) * 32, &Wsb[(kt) % 3][wid * 1024 + 512]);\
  }

  auto compute = [&](const unsigned short* AL, const unsigned short* WL) {
    short8 af[4], bf4[4];
#pragma unroll
    for (int mf = 0; mf < 4; ++mf)
      af[mf] = *(const short8*)&AL[(wm * 64 + mf * 16 + l15) * 32 + l4 * 8];
#pragma unroll
    for (int nf = 0; nf < 4; ++nf)
      bf4[nf] = *(const short8*)&WL[(wn * 64 + nf * 16 + l15) * 32 + l4 * 8];
#pragma unroll
    for (int mf = 0; mf < 4; ++mf)
#pragma unroll
      for (int nf = 0; nf < 4; ++nf)
        acc[mf][nf] = mfma16(af[mf], bf4[nf], acc[mf][nf]);
  };

  // prologue: stage tiles 0,1,2 -> queue [A0,W0,A1,W1,A2,W2] = 12 ops
  ISSA(0); GLW(0);
  ISSA(1); GLW(1);
  ISSA(2); GLW(2);
  VMCNT(10);  // A0 landed
  WRA(0);
  VMCNT(8);   // W0 landed
  LGKM0(); BAR();  // tile 0 ready; queue = [A1,W1,A2,W2] = 8

#pragma unroll
  for (int t = 0; t < 16; ++t) {
    compute(Asb[t % 3], Wsb[t % 3]);
    if (t < 15) {
      // wait A(t+1): queue 8 (t<=13) or 4 (t==14)
      if (t <= 13) { VMCNT(6); } else { VMCNT(2); }
      WRA(t + 1);
      if (t <= 12) {
        ISSA(t + 3);
        VMCNT(6);  // W(t+1) landed: [A(t+2),W(t+2),A(t+3)] remain
      } else if (t == 13) {
        VMCNT(4);  // W(14): [A15,W15] remain
      } else {
        VMCNT(0);  // t==14: W(15) landed, queue empty
      }
      LGKM0(); BAR();  // tile t+1 ready; all waves done reading tile t
      if (t <= 12) GLW(t + 3);  // overwrite Wsb[t%3] (safe post-barrier)
    }
  }

  // C/D layout: col = lane&15, row = (lane>>4)*4 + r  [verified rounds 1-15]
#pragma unroll
  for (int nf = 0; nf < 4; ++nf) {
    const int gn = nBase + wn * 64 + nf * 16 + l15;
    const float bb = bias[gn];
#pragma unroll
    for (int mf = 0; mf < 4; ++mf)
#pragma unroll
      for (int r = 0; r < 4; ++r) {
        const int gm = mBase + wm * 64 + mf * 16 + l4 * 4 + r;
        C[(size_t)gm * ND + gn] = f2bf(acc[mf][nf][r] + bb);
      }
  }
#undef ISSA
#undef WRA
#undef GLW
}

// ==== Wo GEMM + bias + residual(Q): BM=128 x BN=128, BK=32, triple-buffered
// 3-deep gl_lds pipeline (2 ops/tile/wave). LDS 48KB -> 3 blocks/CU.
// Grid 256 = 8 x 32 chunked.
__global__ __launch_bounds__(512, 3) void gemm_wo(
    const unsigned short* __restrict__ ctx, const unsigned short* __restrict__ Wob,
    const float* __restrict__ bo, const float* __restrict__ Qres,
    float* __restrict__ out) {
  __shared__ unsigned short Asb[3][128 * 32];
  __shared__ unsigned short Wsb[3][128 * 32];

  const int bid = blockIdx.x;
  const int lid = (bid & 7) * 32 + (bid >> 3);  // bijective: 256 = 8*32
  const int mt = lid >> 2, nloc = lid & 3;
  const int mBase = mt * 128, nBase = nloc * 128;

  const int tid = threadIdx.x, lane = tid & 63, wid = tid >> 6;
  const int wm = wid >> 2, wn = wid & 3;
  const int l15 = lane & 15, l4 = lane >> 4;

  const unsigned short* Asrc =
      ctx + (size_t)(mBase + wid * 16 + (lane >> 2)) * ND + (lane & 3) * 8;
  const unsigned short* Wsrc =
      Wob + (size_t)(nBase + wid * 16 + (lane >> 2)) * ND + (lane & 3) * 8;

  f32x4 acc[4][2] = {};

#define GLAW(kt)                                              \
  {                                                           \
    gl_lds16(Asrc + (kt) * 32, &Asb[(kt) % 3][wid * 512]);    \
    gl_lds16(Wsrc + (kt) * 32, &Wsb[(kt) % 3][wid * 512]);    \
  }

  auto compute = [&](const unsigned short* AL, const unsigned short* WL) {
    short8 af[4], bf4[2];
#pragma unroll
    for (int mf = 0; mf < 4; ++mf)
      af[mf] = *(const short8*)&AL[(wm * 64 + mf * 16 + l15) * 32 + l4 * 8];
#pragma unroll
    for (int nf = 0; nf < 2; ++nf)
      bf4[nf] = *(const short8*)&WL[(wn * 32 + nf * 16 + l15) * 32 + l4 * 8];
#pragma unroll
    for (int mf = 0; mf < 4; ++mf)
#pragma unroll
      for (int nf = 0; nf < 2; ++nf)
        acc[mf][nf] = mfma16(af[mf], bf4[nf], acc[mf][nf]);
  };

  GLAW(0); GLAW(1); GLAW(2);
  VMCNT(4);  // tile 0 landed
  BAR();

#pragma unroll
  for (int t = 0; t < 16; ++t) {
    compute(Asb[t % 3], Wsb[t % 3]);
    if (t < 15) {
      if (t <= 13) { VMCNT(2); } else { VMCNT(0); }  // tile t+1 landed
      BAR();  // all waves done reading tile t
      if (t <= 12) GLAW(t + 3);  // overwrite buf t%3 (safe post-barrier)
    }
  }

#pragma unroll
  for (int nf = 0; nf < 2; ++nf) {
    const int gn = nBase + wn * 32 + nf * 16 + l15;
    const float bb = bo[gn];
#pragma unroll
    for (int mf = 0; mf < 4; ++mf)
#pragma unroll
      for (int r = 0; r < 4; ++r) {
        const int gm = mBase + wm * 64 + mf * 16 + l4 * 4 + r;
        out[(size_t)gm * ND + gn] =
            acc[mf][nf][r] + bb + Qres[(size_t)gm * ND + gn];
      }
  }
#undef GLAW
}

// ---- attention: one wave per (b,h); lane -> (i=lane>>3, j=lane&7)
__global__ __launch_bounds__(256) void attn_kernel(
    const unsigned short* __restrict__ q, const unsigned short* __restrict__ k,
    const unsigned short* __restrict__ v, const int* __restrict__ mask,
    const float* __restrict__ hyper, float* __restrict__ wout,
    unsigned short* __restrict__ ctx) {
  const int tid = threadIdx.x;
  const int wid = tid >> 6, lane = tid & 63;
  const int t = blockIdx.x * 4 + wid;  // b*16 + h
  const int b = t >> 4, h = t & 15;
  const int i = lane >> 3, j = lane & 7;

  const unsigned short* qrow = q + (size_t)(b * 8 + i) * ND + h * 32;
  const unsigned short* krow = k + (size_t)(b * 8 + j) * ND + h * 32;
  float dot = 0.f;
#pragma unroll
  for (int c = 0; c < 4; ++c) {
    const short8 qv = ((const short8*)qrow)[c];
    const short8 kv = ((const short8*)krow)[c];
#pragma unroll
    for (int e = 0; e < 8; ++e)
      dot += bf2f((unsigned short)qv[e]) * bf2f((unsigned short)kv[e]);
  }
  float score = dot * 0.17677669529663687f;  // 1/sqrt(32)
  if (mask[b * 64 + i * 8 + j]) score = -1e9f;

  float mx = score;
#pragma unroll
  for (int o = 4; o; o >>= 1) mx = fmaxf(mx, __shfl_xor(mx, o, 8));
  const float e = __expf(score - mx);
  float sm = e;
#pragma unroll
  for (int o = 4; o; o >>= 1) sm += __shfl_xor(sm, o, 8);
  const float w = e / sm;
  wout[(size_t)t * 64 + lane] = w;

  const int d0 = (lane & 7) * 4;
  float c0 = 0, c1 = 0, c2 = 0, c3 = 0;
#pragma unroll
  for (int jj = 0; jj < 8; ++jj) {
    const float wj = __shfl(w, jj, 8);
    const ushort4v vv = *(const ushort4v*)(v + (size_t)(b * 8 + jj) * ND + h * 32 + d0);
    c0 += wj * bf2f(vv[0]); c1 += wj * bf2f(vv[1]);
    c2 += wj * bf2f(vv[2]); c3 += wj * bf2f(vv[3]);
  }
  const float4 hv = *(const float4*)(hyper + (size_t)b * 4096 + h * 256 + i * 32 + d0);
  ushort4v co;
  co[0] = f2bf(c0 * hv.x); co[1] = f2bf(c1 * hv.y);
  co[2] = f2bf(c2 * hv.z); co[3] = f2bf(c3 * hv.w);
  *(ushort4v*)(ctx + (size_t)(b * 8 + i) * ND + h * 32 + d0) = co;
}

// ---- in-place: io = LN(io) * g + b  (residual+bias already fused into gemm_wo)
__global__ __launch_bounds__(256) void ln_kernel(float* __restrict__ io,
                                                 const float* __restrict__ g,
                                                 const float* __restrict__ be) {
  const int tid = threadIdx.x, wid = tid >> 6, lane = tid & 63;
  const size_t row = (size_t)blockIdx.x * 4 + wid;
  float* prow = io + row * ND + lane * 8;
  float4 x0 = ((float4*)prow)[0], x1 = ((float4*)prow)[1];
  float s = x0.x + x0.y + x0.z + x0.w + x1.x + x1.y + x1.z + x1.w;
  float sq = x0.x * x0.x + x0.y * x0.y + x0.z * x0.z + x0.w * x0.w +
             x1.x * x1.x + x1.y * x1.y + x1.z * x1.z + x1.w * x1.w;
#pragma unroll
  for (int o = 32; o; o >>= 1) {
    s += __shfl_xor(s, o, 64);
    sq += __shfl_xor(sq, o, 64);
  }
  const float mu = s * (1.f / 512.f);
  const float inv = rsqrtf(sq * (1.f / 512.f) - mu * mu + 1e-5f);
  const float4 g0 = ((const float4*)(g + lane * 8))[0];
  const float4 g1 = ((const float4*)(g + lane * 8))[1];
  const float4 e0 = ((const float4*)(be + lane * 8))[0];
  const float4 e1 = ((const float4*)(be + lane * 8))[1];
  float4 o0, o1;
  o0.x = (x0.x - mu) * inv * g0.x + e0.x; o0.y = (x0.y - mu) * inv * g0.y + e0.y;
  o0.z = (x0.z - mu) * inv * g0.z + e0.z; o0.w = (x0.w - mu) * inv * g0.w + e0.w;
  o1.x = (x1.x - mu) * inv * g1.x + e1.x; o1.y = (x1.y - mu) * inv * g1.y + e1.y;
  o1.z = (x1.z - mu) * inv * g1.z + e1.z; o1.w = (x1.w - mu) * inv * g1.w + e1.w;
  ((float4*)prow)[0] = o0;
  ((float4*)prow)[1] = o1;
}

extern "C" void kernel_launch(void* const* d_in, const int* in_sizes, int n_in,
                              void* d_out, int out_size, void* d_ws, size_t ws_size,
                              hipStream_t stream) {
  const float* Q = (const float*)d_in[0];
  const float* K = (const float*)d_in[1];
  const float* V = (const float*)d_in[2];
  const int* msk = (const int*)d_in[3];
  const float* hyper = (const float*)d_in[4];
  const float* Wq = (const float*)d_in[5];
  const float* bq = (const float*)d_in[6];
  const float* Wk = (const float*)d_in[7];
  const float* bk = (const float*)d_in[8];
  const float* Wv = (const float*)d_in[9];
  const float* bv = (const float*)d_in[10];
  const float* Wo = (const float*)d_in[11];
  const float* bo = (const float*)d_in[12];
  const float* lg = (const float*)d_in[13];
  const float* lb = (const float*)d_in[14];

  float* out = (float*)d_out;           // [8192,512] fp32
  float* wout = out + (size_t)NM * ND;  // [1024,16,8,8] fp32

  const size_t MAT = (size_t)NM * ND;  // elements
  unsigned short* qb = (unsigned short*)d_ws;
  unsigned short* kb = qb + MAT;
  unsigned short* vb = kb + MAT;
  unsigned short* ctxb = vb + MAT;
  unsigned short* Wqb = ctxb + MAT;
  unsigned short* Wkb = Wqb + (size_t)ND * ND;
  unsigned short* Wvb = Wkb + (size_t)ND * ND;
  unsigned short* Wob = Wvb + (size_t)ND * ND;

  convert_w<<<512, 256, 0, stream>>>(Wq, Wk, Wv, Wo, Wqb, Wkb, Wvb, Wob);
  gemm_qkv<<<384, 512, 0, stream>>>(Q, K, V, Wqb, Wkb, Wvb,
                                    bq, bk, bv, qb, kb, vb);
  attn_kernel<<<4096, 256, 0, stream>>>(qb, kb, vb, msk, hyper, wout, ctxb);
  gemm_wo<<<256, 512, 0, stream>>>(ctxb, Wob, bo, Q, out);
  ln_kernel<<<2048, 256, 0, stream>>>(out, lg, lb);
}